// Round 16
// baseline (154.281 us; speedup 1.0000x reference)
//
#include <hip/hip_runtime.h>

// ---------------------------------------------------------------------------
// MultiHeadSelfAttention: GroupNorm(8,256) -> qkv 1x1 -> 8-head attn (N=4096,
// hd=32) -> proj 1x1.  B=2, C=256, H=W=64.
//   - R24: gemm<1> tile 64x32 (BN=32) -> 1024 blocks = 4/CU (was 512 = 2/CU).
//     gemm<1> is a short latency-bound kernel; doubling co-resident blocks
//     cross-fills the barrier-drain slots (R13 lesson: TLP is the lever when
//     no pipe saturates).  Per-block staging halves (RB=1), LDS 24KB.
//   - R23: gn_apply eliminated -- GN fused into gemm<0> B-staging (ga/be LDS
//     table from stats partials; x read directly, bit-identical hn values).
//   - R22: gl16 GEMM staging neutral -> R21 reg-prefetch form kept.
//   - R21: no-atomic GN stats.  R20 combine-fusion reverted (latency-bound
//     gemm<1> can't hide BW work; combine stays a streaming kernel).
//   - R19: gemm<0> 64x128 tile; wcast folded into A staging (RTN cast).
//   - R13: attn: 512-thread blocks (8 waves, one 32KB K/V dbuf), KB=128,
//     gl16 staging, vmcnt(0)+raw barrier.  parts=4.  attn floor ~51us
//     (86% issue-saturated; setprio/stagger/rotation all null).
// ---------------------------------------------------------------------------

typedef _Float16 half8 __attribute__((ext_vector_type(8)));
typedef __fp16   fp16x2 __attribute__((ext_vector_type(2)));  // pkrtz return type
typedef float    f32x4 __attribute__((ext_vector_type(4)));
typedef int      int2v __attribute__((ext_vector_type(2)));
typedef int      int4v __attribute__((ext_vector_type(4)));

__device__ __forceinline__ f32x4 mfma16(half8 a, half8 b, f32x4 c) {
  return __builtin_amdgcn_mfma_f32_16x16x32_f16(a, b, c, 0, 0, 0);
}

#if __has_builtin(__builtin_amdgcn_exp2f)
#define EXP2(x) __builtin_amdgcn_exp2f(x)
#else
#define EXP2(x) exp2f(x)
#endif

__device__ __forceinline__ unsigned short h_bits(_Float16 h) {
  return __builtin_bit_cast(unsigned short, h);
}
__device__ __forceinline__ int h2_bits(fp16x2 h) {
  return __builtin_bit_cast(int, h);
}

// fp32x8 -> fp16x8 with RTN casts (bit-identical to the old wcast kernel).
__device__ __forceinline__ half8 cvt8(const float* p) {
  f32x4 v0 = *(const f32x4*)p;
  f32x4 v1 = *(const f32x4*)(p + 4);
  half8 h;
#pragma unroll
  for (int j = 0; j < 4; ++j) { h[j] = (_Float16)v0[j]; h[4 + j] = (_Float16)v1[j]; }
  return h;
}

// global -> LDS direct copy, 16B per lane (attn staging).
__device__ __forceinline__ void gl16(const _Float16* g, _Float16* l) {
  __builtin_amdgcn_global_load_lds(
      (const __attribute__((address_space(1))) unsigned int*)g,
      (__attribute__((address_space(3))) unsigned int*)l, 16, 0, 0);
}

constexpr float CSCALE = (float)(1.4426950408889634 / 5.656854249492381); // log2(e)/sqrt(32)

// ---------------------------------------------------------------------------
// 1) GroupNorm statistics: grid (16 bg, 32 ch); each block reduces its 4096
//    floats and writes a DISJOINT partial slot (no memset, no atomics).
// ---------------------------------------------------------------------------
__global__ __launch_bounds__(256) void gn_stats(const float* __restrict__ x,
                                                float* __restrict__ stats) {
  const int bg = blockIdx.x, ch = blockIdx.y, tid = threadIdx.x;
  const float* p = x + (size_t)bg * 131072 + (size_t)ch * 4096;
  float s = 0.f, ss = 0.f;
#pragma unroll
  for (int j = 0; j < 4; ++j) {
    f32x4 v = *(const f32x4*)(p + j * 1024 + tid * 4);
#pragma unroll
    for (int k = 0; k < 4; ++k) { s += v[k]; ss += v[k] * v[k]; }
  }
#pragma unroll
  for (int m = 1; m <= 32; m <<= 1) { s += __shfl_xor(s, m); ss += __shfl_xor(ss, m); }
  __shared__ float red[8];
  const int wv = tid >> 6;
  if ((tid & 63) == 0) { red[wv * 2] = s; red[wv * 2 + 1] = ss; }
  __syncthreads();
  if (tid == 0) {
    float S = red[0] + red[2] + red[4] + red[6];
    float SS = red[1] + red[3] + red[5] + red[7];
    stats[(bg * 32 + ch) * 2] = S;
    stats[(bg * 32 + ch) * 2 + 1] = SS;
  }
}

// ---------------------------------------------------------------------------
// 2) fp16 GEMM: out[M][4096] = W[M][256] @ B^T.  W fp32, cast in A staging.
//    64xBN tile, BK=64, frag-order LDS, reg-prefetch single-barrier K-loop.
//    MODE 0 (QKV, M=768, BN=128): B staged DIRECTLY FROM x with fused GN
//      (ga/be LDS table built in prologue from stats partials).  Outputs
//      q*CSCALE,k -> qkT[b][n][512]; v -> v_t[bh][d][n].
//    MODE 1 (proj, M=256, BN=32): B = o16 fp16; fp32 out + bias.
// ---------------------------------------------------------------------------
template <int MODE, int BN>
__global__ __launch_bounds__(256) void gemm_f16(
    const float* __restrict__ Wf, const _Float16* __restrict__ Bm,
    const float* __restrict__ xf, const float* __restrict__ gw,
    const float* __restrict__ gb, const float* __restrict__ stats,
    const float* __restrict__ bias,
    _Float16* __restrict__ qkT, _Float16* __restrict__ v_t,
    float* __restrict__ outp) {
  constexpr int RB = BN / 32;        // B-staging reps
  constexpr int NT = BN / 16;        // n 16-tiles per block
  __shared__ _Float16 a_lds[2][4096];
  __shared__ _Float16 b_lds[2][BN * 64];
  __shared__ float2 gab[MODE == 0 ? 256 : 1];
  __shared__ float mvm[8], mvr[8];
  const int tid = threadIdx.x, lane = tid & 63, wv = tid >> 6;
  const int qq = lane >> 4, ii = lane & 15;
  const int m0 = blockIdx.x * 64, n0 = blockIdx.y * BN, bz = blockIdx.z;

  // staging maps (frag layout addr = idx*8, idx = ((j*2+c)*64 + l)):
  const float* asrc[2];
  int dsta[2];
#pragma unroll
  for (int rep = 0; rep < 2; ++rep) {
    const int idx = tid + 256 * rep;
    dsta[rep] = idx * 8;
    const int j = idx >> 7, c = (idx >> 6) & 1, l = idx & 63;
    const int lq = l >> 4, li = l & 15;
    asrc[rep] = Wf + (size_t)(m0 + 16 * j + li) * 256 + 32 * c + 8 * lq;
  }
  const _Float16* bsrc[RB];  // MODE 1
  const float* xsrc[RB];     // MODE 0
  int cb0[RB];               // MODE 0: c offset within K-tile (0..63)
  int dstb[RB];
#pragma unroll
  for (int rep = 0; rep < RB; ++rep) {
    const int idx = tid + 256 * rep;
    dstb[rep] = idx * 8;
    const int j = idx >> 7, c = (idx >> 6) & 1, l = idx & 63;
    const int lq = l >> 4, li = l & 15;
    const int n = n0 + 16 * j + li;
    if constexpr (MODE == 0) {
      cb0[rep] = 32 * c + 8 * lq;
      xsrc[rep] = xf + ((size_t)(bz * 256 + cb0[rep])) * 4096 + n;
    } else {
      bsrc[rep] = Bm + ((size_t)(bz * 4096 + n)) * 256 + 32 * c + 8 * lq;
    }
  }

  // MODE 0 prologue: group stats reduce (same order as old gn_apply ->
  // identical mean/rstd) + per-channel (ga,be) table.
  if constexpr (MODE == 0) {
    if (tid < 8) {
      const int bg = bz * 8 + tid;
      float S = 0.f, SS = 0.f;
      for (int ch = 0; ch < 32; ++ch) {
        S += stats[(bg * 32 + ch) * 2];
        SS += stats[(bg * 32 + ch) * 2 + 1];
      }
      const float mean = S * (1.f / 131072.f);
      const float var = SS * (1.f / 131072.f) - mean * mean;
      mvm[tid] = mean;
      mvr[tid] = rsqrtf(var + 1e-5f);
    }
    __syncthreads();
    {
      const int c = tid;
      const int g = c >> 5;
      const float ga = gw[c] * mvr[g];
      const float be = gb[c] - mvm[g] * ga;
      gab[c] = make_float2(ga, be);
    }
    __syncthreads();
  }

  // B fetch: MODE 0 reads x + applies GN (bit-identical to old hn values).
  auto fetchB = [&](int rep, int it) -> half8 {
    half8 h;
    if constexpr (MODE == 0) {
      const float* p = xsrc[rep] + (size_t)it * 64 * 4096;
      const int cb = it * 64 + cb0[rep];
#pragma unroll
      for (int i = 0; i < 8; ++i) {
        const float2 ab = gab[cb + i];
        h[i] = (_Float16)(p[(size_t)i * 4096] * ab.x + ab.y);
      }
    } else {
      h = *(const half8*)(bsrc[rep] + it * 64);
    }
    return h;
  };

  f32x4 acc[NT] = {};

  half8 ar[2], br[RB];
#pragma unroll
  for (int rep = 0; rep < 2; ++rep) ar[rep] = cvt8(asrc[rep]);
#pragma unroll
  for (int rep = 0; rep < RB; ++rep) br[rep] = fetchB(rep, 0);
#pragma unroll
  for (int rep = 0; rep < 2; ++rep) *(half8*)(a_lds[0] + dsta[rep]) = ar[rep];
#pragma unroll
  for (int rep = 0; rep < RB; ++rep) *(half8*)(b_lds[0] + dstb[rep]) = br[rep];
  __syncthreads();

  for (int it = 0; it < 4; ++it) {
    const int cur = it & 1;
    if (it < 3) {
      const int ko = (it + 1) * 64;
#pragma unroll
      for (int rep = 0; rep < 2; ++rep) ar[rep] = cvt8(asrc[rep] + ko);
#pragma unroll
      for (int rep = 0; rep < RB; ++rep) br[rep] = fetchB(rep, it + 1);
    }
    half8 ah0 = *(const half8*)(a_lds[cur] + ((wv * 2 + 0) * 64 + lane) * 8);
    half8 ah1 = *(const half8*)(a_lds[cur] + ((wv * 2 + 1) * 64 + lane) * 8);
#pragma unroll
    for (int t = 0; t < NT; ++t) {
      half8 b0 = *(const half8*)(b_lds[cur] + ((t * 2 + 0) * 64 + lane) * 8);
      half8 b1 = *(const half8*)(b_lds[cur] + ((t * 2 + 1) * 64 + lane) * 8);
      acc[t] = mfma16(ah0, b0, acc[t]);
      acc[t] = mfma16(ah1, b1, acc[t]);
    }
    if (it < 3) {
      _Float16* an = a_lds[cur ^ 1];
      _Float16* bn = b_lds[cur ^ 1];
#pragma unroll
      for (int rep = 0; rep < 2; ++rep) *(half8*)(an + dsta[rep]) = ar[rep];
#pragma unroll
      for (int rep = 0; rep < RB; ++rep) *(half8*)(bn + dstb[rep]) = br[rep];
    }
    __syncthreads();
  }

  const int och0 = m0 + 16 * wv + 4 * qq;
  if (MODE == 0) {
    if (m0 < 512) {
      const float sc = (m0 < 256) ? CSCALE : 1.0f;
#pragma unroll
      for (int t = 0; t < NT; ++t) {
        const int n = n0 + 16 * t + ii;
        unsigned short hh[4];
#pragma unroll
        for (int r = 0; r < 4; ++r) {
          hh[r] = h_bits((_Float16)((acc[t][r] + bias[och0 + r]) * sc));
        }
        int2v u;
        u[0] = hh[0] | (hh[1] << 16);
        u[1] = hh[2] | (hh[3] << 16);
        *(int2v*)(qkT + ((size_t)(bz * 4096 + n)) * 512 + och0) = u;
      }
    } else {
#pragma unroll
      for (int t = 0; t < NT; ++t) {
#pragma unroll
        for (int r = 0; r < 4; ++r) {
          const int och = och0 + r;
          const int d = och - 512;
          const int hd_ = d & 31, head = d >> 5;
          const int n = n0 + 16 * t + ii;
          v_t[((size_t)((bz * 8 + head) * 32 + hd_)) * 4096 + n] =
              (_Float16)(acc[t][r] + bias[och]);
        }
      }
    }
  } else {
#pragma unroll
    for (int t = 0; t < NT; ++t) {
#pragma unroll
      for (int r = 0; r < 4; ++r) {
        const int och = och0 + r;
        const int n = n0 + 16 * t + ii;
        outp[((size_t)(bz * 256 + och)) * 4096 + n] = acc[t][r] + bias[och];
      }
    }
  }
}

// ---------------------------------------------------------------------------
// 3) Flash attention (R13 form, best measured): 512-thread blocks (8 waves
//    share one K/V dbuf), KB=128 key tiles, gl16 staging, vmcnt(0) + raw
//    barrier at iter top, stage kb+1 into cur^1 after the barrier.
// ---------------------------------------------------------------------------
__global__ __launch_bounds__(512) void attn_kernel(
    const _Float16* __restrict__ qkT, const _Float16* __restrict__ v_t,
    float* __restrict__ opart, float* __restrict__ lpart, int nkb) {
  __shared__ _Float16 k_lds[2][4096];
  __shared__ _Float16 v_lds[2][4096];
  const int tid = threadIdx.x, lane = tid & 63, wv = tid >> 6;
  const int qq = lane >> 4, ii = lane & 15;
  const int bh = blockIdx.y, b = bh >> 3, h = bh & 7;
  const int n0 = blockIdx.x * 256;
  const int part = blockIdx.z;
  const int key0 = part * (nkb * 128);

  const _Float16* qbase =
      qkT + ((size_t)(b * 4096 + n0 + 32 * wv + ii)) * 512 + h * 32 + 8 * qq;
  half8 qf0 = *(const half8*)qbase;
  half8 qf1 = *(const half8*)(qbase + (size_t)16 * 512);

  const int f = tid >> 6, l = tid & 63;
  const int fq = l >> 4, fi = l & 15;
  const int su = f >> 1, shf = f & 1;
  const int g = 32 * su + 4 * shf + 8 * (fi >> 2) + (fi & 3);
  const _Float16* ksrc =
      qkT + ((size_t)(b * 4096 + key0 + g)) * 512 + 256 + h * 32 + 8 * fq;
  const _Float16* vsrc =
      v_t + ((size_t)(bh * 32 + 16 * shf + fi)) * 4096 + key0 + 32 * su + 8 * fq;
  const int wb = wv * 512;  // wave-uniform LDS element base

  half8 ones8;
#pragma unroll
  for (int j = 0; j < 8; ++j) ones8[j] = (_Float16)1.0f;

  f32x4 o00 = {}, o10 = {}, o01 = {}, o11 = {}, accl0 = {}, accl1 = {};

  // prologue: stage tile 0.
  gl16(ksrc, &k_lds[0][wb]);
  gl16(vsrc, &v_lds[0][wb]);

  for (int kb = 0; kb < nkb; ++kb) {
    const int cur = kb & 1;
    asm volatile("s_waitcnt vmcnt(0)" ::: "memory");
    __builtin_amdgcn_s_barrier();
    if (kb + 1 < nkb) {
      gl16(ksrc + (size_t)(kb + 1) * 65536, &k_lds[cur ^ 1][wb]);
      gl16(vsrc + (size_t)(kb + 1) * 128, &v_lds[cur ^ 1][wb]);
    }
    __builtin_amdgcn_sched_barrier(0);

    const _Float16* kbase = k_lds[cur];
    const _Float16* vbase = v_lds[cur];
#pragma unroll
    for (int u = 0; u < 4; ++u) {
      half8 kfa = *(const half8*)(kbase + u * 1024 + lane * 8);
      half8 kfb = *(const half8*)(kbase + u * 1024 + 512 + lane * 8);
      f32x4 z = {};
      f32x4 sa0 = mfma16(kfa, qf0, z);
      f32x4 sb0 = mfma16(kfb, qf0, z);
      f32x4 sa1 = mfma16(kfa, qf1, z);
      f32x4 sb1 = mfma16(kfb, qf1, z);
      int4v p0, p1;
      p0[0] = h2_bits(__builtin_amdgcn_cvt_pkrtz(EXP2(sa0[0]), EXP2(sa0[1])));
      p0[1] = h2_bits(__builtin_amdgcn_cvt_pkrtz(EXP2(sa0[2]), EXP2(sa0[3])));
      p0[2] = h2_bits(__builtin_amdgcn_cvt_pkrtz(EXP2(sb0[0]), EXP2(sb0[1])));
      p0[3] = h2_bits(__builtin_amdgcn_cvt_pkrtz(EXP2(sb0[2]), EXP2(sb0[3])));
      p1[0] = h2_bits(__builtin_amdgcn_cvt_pkrtz(EXP2(sa1[0]), EXP2(sa1[1])));
      p1[1] = h2_bits(__builtin_amdgcn_cvt_pkrtz(EXP2(sa1[2]), EXP2(sa1[3])));
      p1[2] = h2_bits(__builtin_amdgcn_cvt_pkrtz(EXP2(sb1[0]), EXP2(sb1[1])));
      p1[3] = h2_bits(__builtin_amdgcn_cvt_pkrtz(EXP2(sb1[2]), EXP2(sb1[3])));
      half8 pt0 = __builtin_bit_cast(half8, p0);
      half8 pt1 = __builtin_bit_cast(half8, p1);
      half8 vf0 = *(const half8*)(vbase + u * 1024 + lane * 8);
      half8 vf1 = *(const half8*)(vbase + u * 1024 + 512 + lane * 8);
      o00 = mfma16(vf0, pt0, o00);
      o10 = mfma16(vf1, pt0, o10);
      accl0 = mfma16(ones8, pt0, accl0);
      o01 = mfma16(vf0, pt1, o01);
      o11 = mfma16(vf1, pt1, o11);
      accl1 = mfma16(ones8, pt1, accl1);
    }
  }

#pragma unroll
  for (int hf = 0; hf < 2; ++hf) {
    const f32x4 oa = hf ? o01 : o00;
    const f32x4 ob = hf ? o11 : o10;
    const int q = n0 + 32 * wv + 16 * hf + ii;
    float* base = opart + ((size_t)((part * 2 + b) * 4096 + q)) * 256 + h * 32;
    *(f32x4*)(base + 4 * qq) = oa;
    *(f32x4*)(base + 16 + 4 * qq) = ob;
    if (qq == 0) {
      lpart[((size_t)((part * 2 + b) * 4096 + q)) * 8 + h] = hf ? accl1[0] : accl0[0];
    }
  }
}

// ---------------------------------------------------------------------------
// 4) Combine split-K partials: o = sum(O_p)/sum(l_p), emit fp16.  f32x4
//    vectorized streaming kernel (R20's fusion into gemm<1> regressed).
// ---------------------------------------------------------------------------
__global__ __launch_bounds__(256) void attn_combine(
    const float* __restrict__ opart, const float* __restrict__ lpart,
    _Float16* __restrict__ o16, int parts) {
  const int t = threadIdx.x;
  const int cq = (t & 63) * 4;               // channel quad base
  const int kr = t >> 6;                     // row within block
  const int row = blockIdx.x * 4 + kr;       // (b*4096+q)
  const int b = row >> 12;
  const int q = row & 4095;
  const int hh = cq >> 5;
  f32x4 O = {};
  float L = 0.f;
  for (int p = 0; p < parts; ++p) {
    const size_t rbase = ((size_t)((p * 2 + b) * 4096 + q));
    O += *(const f32x4*)(opart + rbase * 256 + cq);
    L += lpart[rbase * 8 + hh];
  }
  const float inv = 1.0f / L;
  unsigned short hw[4];
#pragma unroll
  for (int j = 0; j < 4; ++j) hw[j] = h_bits((_Float16)(O[j] * inv));
  int2v u;
  u[0] = hw[0] | (hw[1] << 16);
  u[1] = hw[2] | (hw[3] << 16);
  *(int2v*)(o16 + (size_t)row * 256 + cq) = u;
}

// ---------------------------------------------------------------------------
extern "C" void kernel_launch(void* const* d_in, const int* in_sizes, int n_in,
                              void* d_out, int out_size, void* d_ws, size_t ws_size,
                              hipStream_t stream) {
  const float* x     = (const float*)d_in[0];
  const float* gnw   = (const float*)d_in[1];
  const float* gnb   = (const float*)d_in[2];
  const float* wqkv  = (const float*)d_in[3];
  const float* bqkv  = (const float*)d_in[4];
  const float* wproj = (const float*)d_in[5];
  const float* bproj = (const float*)d_in[6];
  float* out = (float*)d_out;

  char* ws = (char*)d_ws;
  size_t off = 0;
  auto alloc = [&](size_t bytes) -> char* {
    char* p = ws + off;
    off += (bytes + 255) & ~(size_t)255;
    return p;
  };
  float*    stats  = (float*)alloc((size_t)16 * 32 * 2 * 4);  // per-chunk partials
  _Float16* o16    = (_Float16*)alloc((size_t)2 * 4096 * 256 * 2);
  _Float16* qkT    = (_Float16*)alloc((size_t)2 * 4096 * 512 * 2);
  _Float16* v_t    = (_Float16*)alloc((size_t)16 * 32 * 4096 * 2);

  // split-K x4 (R13 best); fallback x2 if workspace is tight.
  int parts = 4;
  {
    const size_t need4 = (size_t)8 * 4096 * 256 * 4 + (size_t)8 * 4096 * 8 * 4 + 1024;
    if (off + need4 > ws_size) parts = 2;
  }
  float*    opart  = (float*)alloc((size_t)(parts * 2) * 4096 * 256 * 4);
  float*    lpart  = (float*)alloc((size_t)(parts * 2) * 4096 * 8 * 4);
  if (off > ws_size) return;

  gn_stats<<<dim3(16, 32), 256, 0, stream>>>(x, stats);
  gemm_f16<0, 128><<<dim3(12, 32, 2), 256, 0, stream>>>(
      wqkv, nullptr, x, gnw, gnb, stats, bqkv, qkT, v_t, nullptr);
  const int nkb = 4096 / parts / 128;  // 128-key tiles per split-K part
  attn_kernel<<<dim3(16, 16, parts), 512, 0, stream>>>(qkT, v_t, opart, lpart,
                                                       nkb);
  attn_combine<<<2048, 256, 0, stream>>>(opart, lpart, o16, parts);
  gemm_f16<1, 32><<<dim3(4, 128, 2), 256, 0, stream>>>(
      wproj, o16, nullptr, nullptr, nullptr, nullptr, bproj, nullptr, nullptr,
      out);
}

// Round 17
// 148.706 us; speedup vs baseline: 1.0375x; 1.0375x over previous
//
#include <hip/hip_runtime.h>

// ---------------------------------------------------------------------------
// MultiHeadSelfAttention: GroupNorm(8,256) -> qkv 1x1 -> 8-head attn (N=4096,
// hd=32) -> proj 1x1.  B=2, C=256, H=W=64.
//   - R25: (1) gemm<1> reverted to BN=64 (R24's BN=32 regressed: 4 MFMA/iter
//     per wave, per-block fixed cost dominates).  (2) gemm<0> XCD-aware
//     block swizzle (T1): since R23 it re-reads x 12x (per m0-tile); default
//     linearization round-robins same-n0 blocks across the 8 XCDs so every
//     XCD streams all 16.8MB of x through its 4MB L2.  1D grid 768 with
//     swz=(lin&7)*96+lin>>3 gives each XCD 8 n0-panels (1MB, L2-resident).
//   - R23: gn_apply eliminated -- GN fused into gemm<0> B-staging (ga/be LDS
//     table from stats partials; x read directly, bit-identical hn values).
//   - R21: no-atomic GN stats.  R20 combine-fusion reverted.
//   - R19: gemm<0> 64x128 tile; wcast folded into A staging (RTN cast).
//   - R13: attn: 512-thread blocks (8 waves, one 32KB K/V dbuf), KB=128,
//     gl16 staging, vmcnt(0)+raw barrier.  parts=4.  attn floor ~51us
//     (86% issue-saturated; setprio/stagger/rotation all null).
// ---------------------------------------------------------------------------

typedef _Float16 half8 __attribute__((ext_vector_type(8)));
typedef __fp16   fp16x2 __attribute__((ext_vector_type(2)));  // pkrtz return type
typedef float    f32x4 __attribute__((ext_vector_type(4)));
typedef int      int2v __attribute__((ext_vector_type(2)));
typedef int      int4v __attribute__((ext_vector_type(4)));

__device__ __forceinline__ f32x4 mfma16(half8 a, half8 b, f32x4 c) {
  return __builtin_amdgcn_mfma_f32_16x16x32_f16(a, b, c, 0, 0, 0);
}

#if __has_builtin(__builtin_amdgcn_exp2f)
#define EXP2(x) __builtin_amdgcn_exp2f(x)
#else
#define EXP2(x) exp2f(x)
#endif

__device__ __forceinline__ unsigned short h_bits(_Float16 h) {
  return __builtin_bit_cast(unsigned short, h);
}
__device__ __forceinline__ int h2_bits(fp16x2 h) {
  return __builtin_bit_cast(int, h);
}

// fp32x8 -> fp16x8 with RTN casts (bit-identical to the old wcast kernel).
__device__ __forceinline__ half8 cvt8(const float* p) {
  f32x4 v0 = *(const f32x4*)p;
  f32x4 v1 = *(const f32x4*)(p + 4);
  half8 h;
#pragma unroll
  for (int j = 0; j < 4; ++j) { h[j] = (_Float16)v0[j]; h[4 + j] = (_Float16)v1[j]; }
  return h;
}

// global -> LDS direct copy, 16B per lane (attn staging).
__device__ __forceinline__ void gl16(const _Float16* g, _Float16* l) {
  __builtin_amdgcn_global_load_lds(
      (const __attribute__((address_space(1))) unsigned int*)g,
      (__attribute__((address_space(3))) unsigned int*)l, 16, 0, 0);
}

constexpr float CSCALE = (float)(1.4426950408889634 / 5.656854249492381); // log2(e)/sqrt(32)

// ---------------------------------------------------------------------------
// 1) GroupNorm statistics: grid (16 bg, 32 ch); each block reduces its 4096
//    floats and writes a DISJOINT partial slot (no memset, no atomics).
// ---------------------------------------------------------------------------
__global__ __launch_bounds__(256) void gn_stats(const float* __restrict__ x,
                                                float* __restrict__ stats) {
  const int bg = blockIdx.x, ch = blockIdx.y, tid = threadIdx.x;
  const float* p = x + (size_t)bg * 131072 + (size_t)ch * 4096;
  float s = 0.f, ss = 0.f;
#pragma unroll
  for (int j = 0; j < 4; ++j) {
    f32x4 v = *(const f32x4*)(p + j * 1024 + tid * 4);
#pragma unroll
    for (int k = 0; k < 4; ++k) { s += v[k]; ss += v[k] * v[k]; }
  }
#pragma unroll
  for (int m = 1; m <= 32; m <<= 1) { s += __shfl_xor(s, m); ss += __shfl_xor(ss, m); }
  __shared__ float red[8];
  const int wv = tid >> 6;
  if ((tid & 63) == 0) { red[wv * 2] = s; red[wv * 2 + 1] = ss; }
  __syncthreads();
  if (tid == 0) {
    float S = red[0] + red[2] + red[4] + red[6];
    float SS = red[1] + red[3] + red[5] + red[7];
    stats[(bg * 32 + ch) * 2] = S;
    stats[(bg * 32 + ch) * 2 + 1] = SS;
  }
}

// ---------------------------------------------------------------------------
// 2) fp16 GEMM: out[M][4096] = W[M][256] @ B^T.  W fp32, cast in A staging.
//    64xBN tile, BK=64, frag-order LDS, reg-prefetch single-barrier K-loop.
//    MODE 0 (QKV, M=768, BN=128): 1D grid 768, XCD-chunked swizzle; B staged
//      DIRECTLY FROM x with fused GN (ga/be LDS table from stats partials).
//      Outputs q*CSCALE,k -> qkT[b][n][512]; v -> v_t[bh][d][n].
//    MODE 1 (proj, M=256, BN=64): 3D grid; B = o16 fp16; fp32 out + bias.
// ---------------------------------------------------------------------------
template <int MODE, int BN>
__global__ __launch_bounds__(256) void gemm_f16(
    const float* __restrict__ Wf, const _Float16* __restrict__ Bm,
    const float* __restrict__ xf, const float* __restrict__ gw,
    const float* __restrict__ gb, const float* __restrict__ stats,
    const float* __restrict__ bias,
    _Float16* __restrict__ qkT, _Float16* __restrict__ v_t,
    float* __restrict__ outp) {
  constexpr int RB = BN / 32;        // B-staging reps
  constexpr int NT = BN / 16;        // n 16-tiles per block
  __shared__ _Float16 a_lds[2][4096];
  __shared__ _Float16 b_lds[2][BN * 64];
  __shared__ float2 gab[MODE == 0 ? 256 : 1];
  __shared__ float mvm[8], mvr[8];
  const int tid = threadIdx.x, lane = tid & 63, wv = tid >> 6;
  const int qq = lane >> 4, ii = lane & 15;

  int m0, n0, bz;
  if constexpr (MODE == 0) {
    // XCD-chunked swizzle (768 blocks, 8 XCDs, 96/XCD): each XCD owns 8
    // consecutive n0-panels x all 12 m0 -> x panel set (1MB) is L2-resident.
    const int lin = blockIdx.x;
    const int swz = (lin & 7) * 96 + (lin >> 3);
    const int mi = swz % 12;
    const int rest = swz / 12;        // 0..63
    m0 = mi * 64;
    n0 = (rest & 31) * BN;
    bz = rest >> 5;
  } else {
    m0 = blockIdx.x * 64;
    n0 = blockIdx.y * BN;
    bz = blockIdx.z;
  }

  // staging maps (frag layout addr = idx*8, idx = ((j*2+c)*64 + l)):
  const float* asrc[2];
  int dsta[2];
#pragma unroll
  for (int rep = 0; rep < 2; ++rep) {
    const int idx = tid + 256 * rep;
    dsta[rep] = idx * 8;
    const int j = idx >> 7, c = (idx >> 6) & 1, l = idx & 63;
    const int lq = l >> 4, li = l & 15;
    asrc[rep] = Wf + (size_t)(m0 + 16 * j + li) * 256 + 32 * c + 8 * lq;
  }
  const _Float16* bsrc[RB];  // MODE 1
  const float* xsrc[RB];     // MODE 0
  int cb0[RB];               // MODE 0: c offset within K-tile (0..63)
  int dstb[RB];
#pragma unroll
  for (int rep = 0; rep < RB; ++rep) {
    const int idx = tid + 256 * rep;
    dstb[rep] = idx * 8;
    const int j = idx >> 7, c = (idx >> 6) & 1, l = idx & 63;
    const int lq = l >> 4, li = l & 15;
    const int n = n0 + 16 * j + li;
    if constexpr (MODE == 0) {
      cb0[rep] = 32 * c + 8 * lq;
      xsrc[rep] = xf + ((size_t)(bz * 256 + cb0[rep])) * 4096 + n;
    } else {
      bsrc[rep] = Bm + ((size_t)(bz * 4096 + n)) * 256 + 32 * c + 8 * lq;
    }
  }

  // MODE 0 prologue: group stats reduce (same order as old gn_apply ->
  // identical mean/rstd) + per-channel (ga,be) table.
  if constexpr (MODE == 0) {
    if (tid < 8) {
      const int bg = bz * 8 + tid;
      float S = 0.f, SS = 0.f;
      for (int ch = 0; ch < 32; ++ch) {
        S += stats[(bg * 32 + ch) * 2];
        SS += stats[(bg * 32 + ch) * 2 + 1];
      }
      const float mean = S * (1.f / 131072.f);
      const float var = SS * (1.f / 131072.f) - mean * mean;
      mvm[tid] = mean;
      mvr[tid] = rsqrtf(var + 1e-5f);
    }
    __syncthreads();
    {
      const int c = tid;
      const int g = c >> 5;
      const float ga = gw[c] * mvr[g];
      const float be = gb[c] - mvm[g] * ga;
      gab[c] = make_float2(ga, be);
    }
    __syncthreads();
  }

  // B fetch: MODE 0 reads x + applies GN (bit-identical to old hn values).
  auto fetchB = [&](int rep, int it) -> half8 {
    half8 h;
    if constexpr (MODE == 0) {
      const float* p = xsrc[rep] + (size_t)it * 64 * 4096;
      const int cb = it * 64 + cb0[rep];
#pragma unroll
      for (int i = 0; i < 8; ++i) {
        const float2 ab = gab[cb + i];
        h[i] = (_Float16)(p[(size_t)i * 4096] * ab.x + ab.y);
      }
    } else {
      h = *(const half8*)(bsrc[rep] + it * 64);
    }
    return h;
  };

  f32x4 acc[NT] = {};

  half8 ar[2], br[RB];
#pragma unroll
  for (int rep = 0; rep < 2; ++rep) ar[rep] = cvt8(asrc[rep]);
#pragma unroll
  for (int rep = 0; rep < RB; ++rep) br[rep] = fetchB(rep, 0);
#pragma unroll
  for (int rep = 0; rep < 2; ++rep) *(half8*)(a_lds[0] + dsta[rep]) = ar[rep];
#pragma unroll
  for (int rep = 0; rep < RB; ++rep) *(half8*)(b_lds[0] + dstb[rep]) = br[rep];
  __syncthreads();

  for (int it = 0; it < 4; ++it) {
    const int cur = it & 1;
    if (it < 3) {
      const int ko = (it + 1) * 64;
#pragma unroll
      for (int rep = 0; rep < 2; ++rep) ar[rep] = cvt8(asrc[rep] + ko);
#pragma unroll
      for (int rep = 0; rep < RB; ++rep) br[rep] = fetchB(rep, it + 1);
    }
    half8 ah0 = *(const half8*)(a_lds[cur] + ((wv * 2 + 0) * 64 + lane) * 8);
    half8 ah1 = *(const half8*)(a_lds[cur] + ((wv * 2 + 1) * 64 + lane) * 8);
#pragma unroll
    for (int t = 0; t < NT; ++t) {
      half8 b0 = *(const half8*)(b_lds[cur] + ((t * 2 + 0) * 64 + lane) * 8);
      half8 b1 = *(const half8*)(b_lds[cur] + ((t * 2 + 1) * 64 + lane) * 8);
      acc[t] = mfma16(ah0, b0, acc[t]);
      acc[t] = mfma16(ah1, b1, acc[t]);
    }
    if (it < 3) {
      _Float16* an = a_lds[cur ^ 1];
      _Float16* bn = b_lds[cur ^ 1];
#pragma unroll
      for (int rep = 0; rep < 2; ++rep) *(half8*)(an + dsta[rep]) = ar[rep];
#pragma unroll
      for (int rep = 0; rep < RB; ++rep) *(half8*)(bn + dstb[rep]) = br[rep];
    }
    __syncthreads();
  }

  const int och0 = m0 + 16 * wv + 4 * qq;
  if (MODE == 0) {
    if (m0 < 512) {
      const float sc = (m0 < 256) ? CSCALE : 1.0f;
#pragma unroll
      for (int t = 0; t < NT; ++t) {
        const int n = n0 + 16 * t + ii;
        unsigned short hh[4];
#pragma unroll
        for (int r = 0; r < 4; ++r) {
          hh[r] = h_bits((_Float16)((acc[t][r] + bias[och0 + r]) * sc));
        }
        int2v u;
        u[0] = hh[0] | (hh[1] << 16);
        u[1] = hh[2] | (hh[3] << 16);
        *(int2v*)(qkT + ((size_t)(bz * 4096 + n)) * 512 + och0) = u;
      }
    } else {
#pragma unroll
      for (int t = 0; t < NT; ++t) {
#pragma unroll
        for (int r = 0; r < 4; ++r) {
          const int och = och0 + r;
          const int d = och - 512;
          const int hd_ = d & 31, head = d >> 5;
          const int n = n0 + 16 * t + ii;
          v_t[((size_t)((bz * 8 + head) * 32 + hd_)) * 4096 + n] =
              (_Float16)(acc[t][r] + bias[och]);
        }
      }
    }
  } else {
#pragma unroll
    for (int t = 0; t < NT; ++t) {
#pragma unroll
      for (int r = 0; r < 4; ++r) {
        const int och = och0 + r;
        const int n = n0 + 16 * t + ii;
        outp[((size_t)(bz * 256 + och)) * 4096 + n] = acc[t][r] + bias[och];
      }
    }
  }
}

// ---------------------------------------------------------------------------
// 3) Flash attention (R13 form, best measured): 512-thread blocks (8 waves
//    share one K/V dbuf), KB=128 key tiles, gl16 staging, vmcnt(0) + raw
//    barrier at iter top, stage kb+1 into cur^1 after the barrier.
// ---------------------------------------------------------------------------
__global__ __launch_bounds__(512) void attn_kernel(
    const _Float16* __restrict__ qkT, const _Float16* __restrict__ v_t,
    float* __restrict__ opart, float* __restrict__ lpart, int nkb) {
  __shared__ _Float16 k_lds[2][4096];
  __shared__ _Float16 v_lds[2][4096];
  const int tid = threadIdx.x, lane = tid & 63, wv = tid >> 6;
  const int qq = lane >> 4, ii = lane & 15;
  const int bh = blockIdx.y, b = bh >> 3, h = bh & 7;
  const int n0 = blockIdx.x * 256;
  const int part = blockIdx.z;
  const int key0 = part * (nkb * 128);

  const _Float16* qbase =
      qkT + ((size_t)(b * 4096 + n0 + 32 * wv + ii)) * 512 + h * 32 + 8 * qq;
  half8 qf0 = *(const half8*)qbase;
  half8 qf1 = *(const half8*)(qbase + (size_t)16 * 512);

  const int f = tid >> 6, l = tid & 63;
  const int fq = l >> 4, fi = l & 15;
  const int su = f >> 1, shf = f & 1;
  const int g = 32 * su + 4 * shf + 8 * (fi >> 2) + (fi & 3);
  const _Float16* ksrc =
      qkT + ((size_t)(b * 4096 + key0 + g)) * 512 + 256 + h * 32 + 8 * fq;
  const _Float16* vsrc =
      v_t + ((size_t)(bh * 32 + 16 * shf + fi)) * 4096 + key0 + 32 * su + 8 * fq;
  const int wb = wv * 512;  // wave-uniform LDS element base

  half8 ones8;
#pragma unroll
  for (int j = 0; j < 8; ++j) ones8[j] = (_Float16)1.0f;

  f32x4 o00 = {}, o10 = {}, o01 = {}, o11 = {}, accl0 = {}, accl1 = {};

  // prologue: stage tile 0.
  gl16(ksrc, &k_lds[0][wb]);
  gl16(vsrc, &v_lds[0][wb]);

  for (int kb = 0; kb < nkb; ++kb) {
    const int cur = kb & 1;
    asm volatile("s_waitcnt vmcnt(0)" ::: "memory");
    __builtin_amdgcn_s_barrier();
    if (kb + 1 < nkb) {
      gl16(ksrc + (size_t)(kb + 1) * 65536, &k_lds[cur ^ 1][wb]);
      gl16(vsrc + (size_t)(kb + 1) * 128, &v_lds[cur ^ 1][wb]);
    }
    __builtin_amdgcn_sched_barrier(0);

    const _Float16* kbase = k_lds[cur];
    const _Float16* vbase = v_lds[cur];
#pragma unroll
    for (int u = 0; u < 4; ++u) {
      half8 kfa = *(const half8*)(kbase + u * 1024 + lane * 8);
      half8 kfb = *(const half8*)(kbase + u * 1024 + 512 + lane * 8);
      f32x4 z = {};
      f32x4 sa0 = mfma16(kfa, qf0, z);
      f32x4 sb0 = mfma16(kfb, qf0, z);
      f32x4 sa1 = mfma16(kfa, qf1, z);
      f32x4 sb1 = mfma16(kfb, qf1, z);
      int4v p0, p1;
      p0[0] = h2_bits(__builtin_amdgcn_cvt_pkrtz(EXP2(sa0[0]), EXP2(sa0[1])));
      p0[1] = h2_bits(__builtin_amdgcn_cvt_pkrtz(EXP2(sa0[2]), EXP2(sa0[3])));
      p0[2] = h2_bits(__builtin_amdgcn_cvt_pkrtz(EXP2(sb0[0]), EXP2(sb0[1])));
      p0[3] = h2_bits(__builtin_amdgcn_cvt_pkrtz(EXP2(sb0[2]), EXP2(sb0[3])));
      p1[0] = h2_bits(__builtin_amdgcn_cvt_pkrtz(EXP2(sa1[0]), EXP2(sa1[1])));
      p1[1] = h2_bits(__builtin_amdgcn_cvt_pkrtz(EXP2(sa1[2]), EXP2(sa1[3])));
      p1[2] = h2_bits(__builtin_amdgcn_cvt_pkrtz(EXP2(sb1[0]), EXP2(sb1[1])));
      p1[3] = h2_bits(__builtin_amdgcn_cvt_pkrtz(EXP2(sb1[2]), EXP2(sb1[3])));
      half8 pt0 = __builtin_bit_cast(half8, p0);
      half8 pt1 = __builtin_bit_cast(half8, p1);
      half8 vf0 = *(const half8*)(vbase + u * 1024 + lane * 8);
      half8 vf1 = *(const half8*)(vbase + u * 1024 + 512 + lane * 8);
      o00 = mfma16(vf0, pt0, o00);
      o10 = mfma16(vf1, pt0, o10);
      accl0 = mfma16(ones8, pt0, accl0);
      o01 = mfma16(vf0, pt1, o01);
      o11 = mfma16(vf1, pt1, o11);
      accl1 = mfma16(ones8, pt1, accl1);
    }
  }

#pragma unroll
  for (int hf = 0; hf < 2; ++hf) {
    const f32x4 oa = hf ? o01 : o00;
    const f32x4 ob = hf ? o11 : o10;
    const int q = n0 + 32 * wv + 16 * hf + ii;
    float* base = opart + ((size_t)((part * 2 + b) * 4096 + q)) * 256 + h * 32;
    *(f32x4*)(base + 4 * qq) = oa;
    *(f32x4*)(base + 16 + 4 * qq) = ob;
    if (qq == 0) {
      lpart[((size_t)((part * 2 + b) * 4096 + q)) * 8 + h] = hf ? accl1[0] : accl0[0];
    }
  }
}

// ---------------------------------------------------------------------------
// 4) Combine split-K partials: o = sum(O_p)/sum(l_p), emit fp16.  f32x4
//    vectorized streaming kernel (R20's fusion into gemm<1> regressed).
// ---------------------------------------------------------------------------
__global__ __launch_bounds__(256) void attn_combine(
    const float* __restrict__ opart, const float* __restrict__ lpart,
    _Float16* __restrict__ o16, int parts) {
  const int t = threadIdx.x;
  const int cq = (t & 63) * 4;               // channel quad base
  const int kr = t >> 6;                     // row within block
  const int row = blockIdx.x * 4 + kr;       // (b*4096+q)
  const int b = row >> 12;
  const int q = row & 4095;
  const int hh = cq >> 5;
  f32x4 O = {};
  float L = 0.f;
  for (int p = 0; p < parts; ++p) {
    const size_t rbase = ((size_t)((p * 2 + b) * 4096 + q));
    O += *(const f32x4*)(opart + rbase * 256 + cq);
    L += lpart[rbase * 8 + hh];
  }
  const float inv = 1.0f / L;
  unsigned short hw[4];
#pragma unroll
  for (int j = 0; j < 4; ++j) hw[j] = h_bits((_Float16)(O[j] * inv));
  int2v u;
  u[0] = hw[0] | (hw[1] << 16);
  u[1] = hw[2] | (hw[3] << 16);
  *(int2v*)(o16 + (size_t)row * 256 + cq) = u;
}

// ---------------------------------------------------------------------------
extern "C" void kernel_launch(void* const* d_in, const int* in_sizes, int n_in,
                              void* d_out, int out_size, void* d_ws, size_t ws_size,
                              hipStream_t stream) {
  const float* x     = (const float*)d_in[0];
  const float* gnw   = (const float*)d_in[1];
  const float* gnb   = (const float*)d_in[2];
  const float* wqkv  = (const float*)d_in[3];
  const float* bqkv  = (const float*)d_in[4];
  const float* wproj = (const float*)d_in[5];
  const float* bproj = (const float*)d_in[6];
  float* out = (float*)d_out;

  char* ws = (char*)d_ws;
  size_t off = 0;
  auto alloc = [&](size_t bytes) -> char* {
    char* p = ws + off;
    off += (bytes + 255) & ~(size_t)255;
    return p;
  };
  float*    stats  = (float*)alloc((size_t)16 * 32 * 2 * 4);  // per-chunk partials
  _Float16* o16    = (_Float16*)alloc((size_t)2 * 4096 * 256 * 2);
  _Float16* qkT    = (_Float16*)alloc((size_t)2 * 4096 * 512 * 2);
  _Float16* v_t    = (_Float16*)alloc((size_t)16 * 32 * 4096 * 2);

  // split-K x4 (R13 best); fallback x2 if workspace is tight.
  int parts = 4;
  {
    const size_t need4 = (size_t)8 * 4096 * 256 * 4 + (size_t)8 * 4096 * 8 * 4 + 1024;
    if (off + need4 > ws_size) parts = 2;
  }
  float*    opart  = (float*)alloc((size_t)(parts * 2) * 4096 * 256 * 4);
  float*    lpart  = (float*)alloc((size_t)(parts * 2) * 4096 * 8 * 4);
  if (off > ws_size) return;

  gn_stats<<<dim3(16, 32), 256, 0, stream>>>(x, stats);
  gemm_f16<0, 128><<<768, 256, 0, stream>>>(
      wqkv, nullptr, x, gnw, gnb, stats, bqkv, qkT, v_t, nullptr);
  const int nkb = 4096 / parts / 128;  // 128-key tiles per split-K part
  attn_kernel<<<dim3(16, 16, parts), 512, 0, stream>>>(qkT, v_t, opart, lpart,
                                                       nkb);
  attn_combine<<<2048, 256, 0, stream>>>(opart, lpart, o16, parts);
  gemm_f16<1, 64><<<dim3(4, 64, 2), 256, 0, stream>>>(
      wproj, o16, nullptr, nullptr, nullptr, nullptr, bproj, nullptr, nullptr,
      out);
}